// Round 16
// baseline (428.495 us; speedup 1.0000x reference)
//
#include <hip/hip_runtime.h>
#include <math.h>

#define SEQ 1024
#define EMB 768
#define NHEAD 12
#define HDIM 64
#define NLAYER 4
#define FFDIM 2048
#define BATCH 2
#define ROWS (BATCH * SEQ)   // 2048
#define BH (BATCH * NHEAD)   // 24

using f16 = _Float16;
using f16x4 = __attribute__((ext_vector_type(4))) _Float16;
using f16x8 = __attribute__((ext_vector_type(8))) _Float16;
using f32x4 = __attribute__((ext_vector_type(4))) float;
using f32x16 = __attribute__((ext_vector_type(16))) float;
typedef unsigned long long u64;

__device__ inline void gload16(const void* g, void* l) {
    __builtin_amdgcn_global_load_lds((const __attribute__((address_space(1))) unsigned*)g,
                                     (__attribute__((address_space(3))) unsigned*)l, 16, 0, 0);
}

// ---------------- prep: weight cast (all layers) + embed + mask table -------
__global__ void prep_kernel(const float* __restrict__ Wq, int na,   // float4 units
                            const float* __restrict__ W1, int nb,
                            const float* __restrict__ W2, int nc,
                            f16* __restrict__ oq, f16* __restrict__ o1, f16* __restrict__ o2,
                            const float* __restrict__ x,
                            const float* __restrict__ tpe,
                            float* __restrict__ h32,
                            f16* __restrict__ h16,
                            u64* __restrict__ mtab,
                            const int* __restrict__ tt_p,
                            const int* __restrict__ rtc_p) {
    const int ncast = na + nb + nc;
    const int nembed = BATCH * SEQ * EMB;
    const int nmask = SEQ * 16;
    const int total = ncast + nembed + nmask;
    const int nt = *tt_p + 1;
    const int rtc = *rtc_p;
    for (int i = blockIdx.x * blockDim.x + threadIdx.x; i < total;
         i += gridDim.x * blockDim.x) {
        if (i < ncast) {
            const float* src;
            f16* dst;
            int off;
            if (i < na)            { src = Wq; dst = oq; off = i; }
            else if (i < na + nb)  { src = W1; dst = o1; off = i - na; }
            else                   { src = W2; dst = o2; off = i - na - nb; }
            float4 v = ((const float4*)src)[off];
            f16x4 o;
            o[0] = (f16)v.x; o[1] = (f16)v.y; o[2] = (f16)v.z; o[3] = (f16)v.w;
            ((f16x4*)dst)[off] = o;
        } else if (i < ncast + nembed) {
            int idx = i - ncast;
            int e = idx % EMB;
            int s = (idx / EMB) % SEQ;
            float val;
            if (s < rtc * nt) {
                int p = s / nt;
                int t = s % nt;
                int i2 = e & ~1;
                float div = __expf((float)i2 * -0.0119926314f);  // -ln(10000)/768
                float ang = (float)p * div;
                float pe = (e & 1) ? __cosf(ang) : __sinf(ang);
                val = x[idx] + pe + tpe[t * EMB + e];
            } else {
                val = 0.0f;
            }
            h32[idx] = val;
            h16[idx] = (f16)val;
        } else {
            int idx = i - ncast - nembed;
            int ii = idx >> 4, jt = idx & 15;
            int id = ii / nt, im = ii % nt;
            int iok = (ii < rtc * nt);
            u64 m = 0;
            for (int k = 0; k < 64; k++) {
                int j = jt * 64 + k;
                int jd = j / nt, jm = j % nt;
                bool same = (id == jd) && (id < rtc) && (im >= jm);
                bool sv   = (jm == 0) && (jd < rtc) && (ii > j) && iok;
                if (same || sv) m |= (1ull << k);
            }
            mtab[idx] = m;
        }
    }
}

// ---------------- MFMA GEMM (32x32x16): C = A @ W^T (+ bias) -----------------
// 512 threads = 8 waves sharing ONE staged 128x128 tile, output split 4(M)x2(N)
// per wave (32x64 each). LDS double-buffered (64KB -> 2 blocks/CU co-resident),
// prefetch-before-compute, ONE barrier per K-step.
// OUT: 1 = f16 out (+bias, opt GELU); 2 = qkv split (Q,K f16 stride 2E +bias,
//      V transposed +bias -> vtg[b,h,d,s]); 3 = f16 raw-acc partials to
//      Ch + z*ROWS*N (split-K; bias added downstream)
template<int ACT, int OUT>
__global__ __launch_bounds__(512) void gemm_f16(const f16* __restrict__ A,
                                                const f16* __restrict__ W,
                                                const float* __restrict__ bias,
                                                f16* __restrict__ Ch,
                                                f16* __restrict__ vtg,
                                                int M, int N, int K) {
    __shared__ f16 As[2][128 * 64];
    __shared__ f16 Ws[2][128 * 64];
    const int tid = threadIdx.x, lane = tid & 63, wave = tid >> 6;  // 0..7
    // XCD-aware block swizzle (bijective when nwg % 8 == 0)
    const int gx = gridDim.x;
    const int nwg = gx * gridDim.y;
    int orig = blockIdx.y * gx + blockIdx.x;
    int nid = (nwg & 7) ? orig : ((orig & 7) * (nwg >> 3) + (orig >> 3));
    const int bm = (nid / gx) * 128, bn = (nid % gx) * 128;
    const int l31 = lane & 31, l32 = lane >> 5;
    const int wm = (wave >> 1) * 32, wn = (wave & 1) * 64;  // wave's 32x64 sub-tile
    const int srow = lane >> 3, sslot = lane & 7;
    const int klen = K / gridDim.z;
    const int kbeg = blockIdx.z * klen;
    const int nsteps = klen >> 6;

    f32x16 acc[2];
#pragma unroll
    for (int ni = 0; ni < 2; ni++)
#pragma unroll
        for (int e = 0; e < 16; e++) acc[ni][e] = 0.f;

    // prologue: stage buffer 0 (8 waves x 16 rows each, A and W)
#pragma unroll
    for (int i = 0; i < 2; i++) {
        int R0 = wave * 16 + i * 8;
        int row = R0 + srow;
        int gs = (sslot ^ (row & 7)) << 3;
        gload16(A + (size_t)(bm + row) * K + kbeg + gs, As[0] + R0 * 64);
        gload16(W + (size_t)(bn + row) * K + kbeg + gs, Ws[0] + R0 * 64);
    }
    __syncthreads();

    int cur = 0;
    for (int t = 0; t < nsteps; t++) {
        if (t + 1 < nsteps) {
            int k1 = kbeg + (t + 1) * 64;
            int nxt = cur ^ 1;
#pragma unroll
            for (int i = 0; i < 2; i++) {
                int R0 = wave * 16 + i * 8;
                int row = R0 + srow;
                int gs = (sslot ^ (row & 7)) << 3;
                gload16(A + (size_t)(bm + row) * K + k1 + gs, As[nxt] + R0 * 64);
                gload16(W + (size_t)(bn + row) * K + k1 + gs, Ws[nxt] + R0 * 64);
            }
        }
#pragma unroll
        for (int ks = 0; ks < 4; ks++) {
            int kslot = ks * 2 + l32;   // 8 f16 k-elems per slot
            f16x8 a, b[2];
            {
                int row = wm + l31;
                a = *(const f16x8*)(As[cur] + row * 64 + ((kslot ^ (row & 7)) << 3));
            }
#pragma unroll
            for (int ni = 0; ni < 2; ni++) {
                int row = wn + ni * 32 + l31;
                b[ni] = *(const f16x8*)(Ws[cur] + row * 64 + ((kslot ^ (row & 7)) << 3));
            }
#pragma unroll
            for (int ni = 0; ni < 2; ni++)
                acc[ni] = __builtin_amdgcn_mfma_f32_32x32x16_f16(a, b[ni], acc[ni], 0, 0, 0);
        }
        __syncthreads();
        cur ^= 1;
    }

    // epilogue: C row = (reg&3) + 8*(reg>>2) + 4*(lane>>5), col = lane&31
#pragma unroll
    for (int ni = 0; ni < 2; ni++) {
        int nbase = bn + wn + ni * 32;
        int n = nbase + l31;
        if (OUT == 3) {
            f16* dst = Ch + (size_t)blockIdx.z * ROWS * N;
#pragma unroll
            for (int reg = 0; reg < 16; reg++) {
                int m = bm + wm + (reg & 3) + 8 * (reg >> 2) + 4 * l32;
                dst[(size_t)m * N + n] = (f16)acc[ni][reg];
            }
        } else {
            float bv = bias[n];
            if (OUT != 2 || nbase < 2 * EMB) {
                int cstride = (OUT == 2) ? 2 * EMB : N;
#pragma unroll
                for (int reg = 0; reg < 16; reg++) {
                    int m = bm + wm + (reg & 3) + 8 * (reg >> 2) + 4 * l32;
                    float v = acc[ni][reg] + bv;
                    if (ACT) v = 0.5f * v * (1.0f + erff(v * 0.70710678118654752f));
                    Ch[(size_t)m * cstride + n] = (f16)v;
                }
            } else {
                // V third: write transposed vtg[((b*H + h)*64 + d) * SEQ + s]
                int d = n - 2 * EMB;
                int hh = d >> 6, dd = d & 63;
#pragma unroll
                for (int q = 0; q < 4; q++) {
                    int m0 = bm + wm + 8 * q + 4 * l32;
                    int bb = m0 >> 10, s0 = m0 & (SEQ - 1);
                    f16x4 pack;
#pragma unroll
                    for (int r = 0; r < 4; r++) pack[r] = (f16)(acc[ni][4 * q + r] + bv);
                    *(f16x4*)(vtg + ((size_t)((bb * NHEAD + hh) * HDIM + dd)) * SEQ + s0) = pack;
                }
            }
        }
    }
}

// ---------------- flash attention (full chain, dbuf, mask table) ------------
// grid: (S/64, BH); qt reversed (long chains first). Single chunk per q-tile:
// the j-chain (<=16 dbuf-prefetched steps) runs in one block, so the output is
// normalized IN-KERNEL (f32) and written once -- no pm/pl/combine needed.
// All 384 blocks are co-resident (48KB LDS -> 3 blocks/CU).
__global__ __launch_bounds__(256) void attn_part(const f16* __restrict__ qk,  // (B*S, 2E)
                                                 const f16* __restrict__ vtg, // (B,H,64,S)
                                                 const u64* __restrict__ mtab,// [SEQ][16]
                                                 f16* __restrict__ po) {      // [BH][SEQ][64] normalized
    const int qt = gridDim.x - 1 - blockIdx.x;   // long chains first
    const int bh = blockIdx.y;
    const int b = bh / NHEAD, hh = bh % NHEAD;
    const int q0 = qt * 64;

    __shared__ f16 Qs[64 * 64];
    __shared__ f16 Ks[2][64 * 64];
    __shared__ f16 VT[2][64 * 64];
    __shared__ f16 Ps[4 * 16 * 64];

    const int tid = threadIdx.x, lane = tid & 63, wave = tid >> 6;
    const int l15 = lane & 15, l16 = lane >> 4;
    const int RS = 2 * EMB;
    const f16* vth = vtg + (size_t)(b * NHEAD + hh) * HDIM * SEQ;
    const float SCALE2 = 0.125f * 1.44269504088896f;   // scale * log2(e)

    // ---- stage Q tile + first K/V tile (pre-swizzled source) ----
#pragma unroll
    for (int it = 0; it < 2; it++) {
        int R0 = wave * 16 + it * 8;
        int row = R0 + (lane >> 3), slot = lane & 7;
        int gs = (slot ^ (row & 7)) << 3;
        gload16(qk + (size_t)(b * SEQ + q0 + row) * RS + hh * HDIM + gs, Qs + R0 * 64);
        gload16(qk + (size_t)(b * SEQ + row) * RS + EMB + hh * HDIM + gs, Ks[0] + R0 * 64);
        gload16(vth + (size_t)row * SEQ + gs, VT[0] + R0 * 64);
    }
    __syncthreads();

    f16x8 qa[2];
#pragma unroll
    for (int ks = 0; ks < 2; ks++) {
        int row = wave * 16 + l15;
        int kslot = l16 + ks * 4;
        qa[ks] = *(const f16x8*)(Qs + row * 64 + ((kslot ^ (row & 7)) << 3));
    }

    f16x8 ones;
#pragma unroll
    for (int i = 0; i < 8; i++) ones[i] = (f16)1.0f;

    float mrow[4];
    f32x4 o[4], osum;
    int iglob[4];
#pragma unroll
    for (int r = 0; r < 4; r++) {
        mrow[r] = -1e30f;
        iglob[r] = q0 + wave * 16 + l16 * 4 + r;
    }
#pragma unroll
    for (int nf = 0; nf < 4; nf++) o[nf] = (f32x4){0.f, 0.f, 0.f, 0.f};
    osum = (f32x4){0.f, 0.f, 0.f, 0.f};

    for (int jt = 0; jt <= qt; jt++) {
        const int cur = jt & 1;
        // ---- issue next tile's async loads (hidden under compute) ----
        if (jt < qt) {
            const int nxt = cur ^ 1;
            const int jn0 = (jt + 1) * 64;
#pragma unroll
            for (int it = 0; it < 2; it++) {
                int R0 = wave * 16 + it * 8;
                int row = R0 + (lane >> 3), slot = lane & 7;
                int gs = (slot ^ (row & 7)) << 3;
                gload16(qk + (size_t)(b * SEQ + jn0 + row) * RS + EMB + hh * HDIM + gs,
                        Ks[nxt] + R0 * 64);
                gload16(vth + (size_t)row * SEQ + jn0 + gs, VT[nxt] + R0 * 64);
            }
        }

        // ---- fetch mask words for this j-tile ----
        unsigned mlo[4], mhi[4];
#pragma unroll
        for (int r = 0; r < 4; r++) {
            u64 mk = mtab[iglob[r] * 16 + jt];
            mlo[r] = (unsigned)mk;
            mhi[r] = (unsigned)(mk >> 32);
        }

        // ---- S = Q K^T ----
        f32x4 s[4];
        __builtin_amdgcn_s_setprio(1);
#pragma unroll
        for (int nf = 0; nf < 4; nf++) {
            s[nf] = (f32x4){0.f, 0.f, 0.f, 0.f};
#pragma unroll
            for (int ks = 0; ks < 2; ks++) {
                int row = nf * 16 + l15;
                int kslot = l16 + ks * 4;
                f16x8 kb = *(const f16x8*)(Ks[cur] + row * 64 + ((kslot ^ (row & 7)) << 3));
                s[nf] = __builtin_amdgcn_mfma_f32_16x16x32_f16(qa[ks], kb, s[nf], 0, 0, 0);
            }
        }
        __builtin_amdgcn_s_setprio(0);

        // ---- mask (bit-table) + online softmax (base-2) ----
        float p[4][4];
        float tmax[4] = {-1e30f, -1e30f, -1e30f, -1e30f};
#pragma unroll
        for (int nf = 0; nf < 4; nf++) {
            int sh = (nf & 1) * 16 + l15;
#pragma unroll
            for (int r = 0; r < 4; r++) {
                unsigned w = (nf & 2) ? mhi[r] : mlo[r];
                bool allowed = (w >> sh) & 1;
                float val = allowed ? s[nf][r] * SCALE2 : -1e30f;
                p[nf][r] = val;
                tmax[r] = fmaxf(tmax[r], val);
            }
        }
#pragma unroll
        for (int r = 0; r < 4; r++) {
            tmax[r] = fmaxf(tmax[r], __shfl_xor(tmax[r], 1));
            tmax[r] = fmaxf(tmax[r], __shfl_xor(tmax[r], 2));
            tmax[r] = fmaxf(tmax[r], __shfl_xor(tmax[r], 4));
            tmax[r] = fmaxf(tmax[r], __shfl_xor(tmax[r], 8));
        }
        float alpha[4], meff[4];
#pragma unroll
        for (int r = 0; r < 4; r++) {
            float mn = fmaxf(mrow[r], tmax[r]);
            alpha[r] = exp2f(mrow[r] - mn);
            mrow[r] = mn;
            meff[r] = (mn <= -1e29f) ? 0.f : mn;
        }
#pragma unroll
        for (int nf = 0; nf < 4; nf++)
#pragma unroll
            for (int r = 0; r < 4; r++)
                p[nf][r] = exp2f(p[nf][r] - meff[r]);
#pragma unroll
        for (int r = 0; r < 4; r++) osum[r] *= alpha[r];
#pragma unroll
        for (int nf = 0; nf < 4; nf++)
#pragma unroll
            for (int r = 0; r < 4; r++) o[nf][r] *= alpha[r];

        // ---- P -> per-wave LDS (wave-local, lgkm-ordered) ----
        f16* P = Ps + wave * 16 * 64;
#pragma unroll
        for (int nf = 0; nf < 4; nf++)
#pragma unroll
            for (int r = 0; r < 4; r++) {
                int prow = l16 * 4 + r;
                int pcol = nf * 16 + l15;
                P[prow * 64 + (((pcol >> 3) ^ (prow & 7)) << 3) + (pcol & 7)] = (f16)p[nf][r];
            }

        // ---- O += P @ V ; lsum += P @ 1 (matrix pipe row-sum) ----
        __builtin_amdgcn_s_setprio(1);
#pragma unroll
        for (int ks = 0; ks < 2; ks++) {
            int kslot = l16 + ks * 4;
            int prow = l15;
            f16x8 pa = *(const f16x8*)(P + prow * 64 + ((kslot ^ (prow & 7)) << 3));
            osum = __builtin_amdgcn_mfma_f32_16x16x32_f16(pa, ones, osum, 0, 0, 0);
#pragma unroll
            for (int nf = 0; nf < 4; nf++) {
                int vrow = nf * 16 + l15;
                f16x8 vb = *(const f16x8*)(VT[cur] + vrow * 64 + ((kslot ^ (vrow & 7)) << 3));
                o[nf] = __builtin_amdgcn_mfma_f32_16x16x32_f16(pa, vb, o[nf], 0, 0, 0);
            }
        }
        __builtin_amdgcn_s_setprio(0);
        __syncthreads();
    }

    // ---- normalize in f32 and write final attention output ----
    const size_t base = (size_t)bh * SEQ;
#pragma unroll
    for (int r = 0; r < 4; r++) {
        int i = q0 + wave * 16 + l16 * 4 + r;
        float inv = (osum[r] > 0.f) ? 1.0f / osum[r] : 0.0f;
#pragma unroll
        for (int nf = 0; nf < 4; nf++)
            po[(base + i) * 64 + nf * 16 + l15] = (f16)(o[nf][r] * inv);
    }
}

// ---------------- LN( h + attn_out ), wave-per-row ---------------------------
__global__ __launch_bounds__(256) void add_ln_attn(const float* __restrict__ X,
                                                   const f16* __restrict__ po,  // [BH][SEQ][64]
                                                   const float* __restrict__ w,
                                                   const float* __restrict__ bsh,
                                                   float* __restrict__ out32,
                                                   f16* __restrict__ out16) {
    const int row = blockIdx.x * 4 + (threadIdx.x >> 6);
    const int lane = threadIdx.x & 63;
    const int b = row >> 10, i = row & (SEQ - 1);
    const float* xr = X + (size_t)row * EMB;
    float4 v[3];
    float s = 0.f;
#pragma unroll
    for (int t = 0; t < 3; t++) {
        int e = t * 256 + lane * 4;
        int hh = e >> 6, d = e & 63;
        f16x4 pv = *(const f16x4*)(po + ((size_t)(b * NHEAD + hh) * SEQ + i) * 64 + d);
        float4 a = *(const float4*)(xr + e);
        a.x += (float)pv[0]; a.y += (float)pv[1];
        a.z += (float)pv[2]; a.w += (float)pv[3];
        v[t] = a;
        s += a.x + a.y + a.z + a.w;
    }
#pragma unroll
    for (int k = 1; k < 64; k <<= 1) s += __shfl_xor(s, k);
    float mu = s * (1.0f / EMB);
    float s2 = 0.f;
#pragma unroll
    for (int t = 0; t < 3; t++) {
        float dx = v[t].x - mu, dy = v[t].y - mu, dz = v[t].z - mu, dw = v[t].w - mu;
        s2 += dx * dx + dy * dy + dz * dz + dw * dw;
    }
#pragma unroll
    for (int k = 1; k < 64; k <<= 1) s2 += __shfl_xor(s2, k);
    float inv = rsqrtf(s2 * (1.0f / EMB) + 1e-5f);
#pragma unroll
    for (int t = 0; t < 3; t++) {
        int e = t * 256 + lane * 4;
        float4 wv = *(const float4*)(w + e);
        float4 bv = *(const float4*)(bsh + e);
        float4 o;
        o.x = (v[t].x - mu) * inv * wv.x + bv.x;
        o.y = (v[t].y - mu) * inv * wv.y + bv.y;
        o.z = (v[t].z - mu) * inv * wv.z + bv.z;
        o.w = (v[t].w - mu) * inv * wv.w + bv.w;
        *(float4*)(out32 + (size_t)row * EMB + e) = o;
        f16x4 hh;
        hh[0] = (f16)o.x; hh[1] = (f16)o.y; hh[2] = (f16)o.z; hh[3] = (f16)o.w;
        *(f16x4*)(out16 + (size_t)row * EMB + e) = hh;
    }
}

// ---------------- LN( h + bias + sum of 2 f16 split-K partials ) ------------
// FINAL=1: additionally apply the final LayerNorm (lnf) in-register and write
// ONLY the f32 output (fuses the last ln_final launch).
template<int FINAL>
__global__ __launch_bounds__(256) void add_ln_split(const float* __restrict__ X,
                                                    const f16* __restrict__ part, // 2x ROWS*EMB f16
                                                    const float* __restrict__ bias,
                                                    const float* __restrict__ w,
                                                    const float* __restrict__ bsh,
                                                    const float* __restrict__ wf,   // lnf
                                                    const float* __restrict__ bf,
                                                    float* __restrict__ out32,
                                                    f16* __restrict__ out16) {
    const int row = blockIdx.x * 4 + (threadIdx.x >> 6);
    const int lane = threadIdx.x & 63;
    const float* xr = X + (size_t)row * EMB;
    float4 v[3];
    float s = 0.f;
#pragma unroll
    for (int t = 0; t < 3; t++) {
        int e = t * 256 + lane * 4;
        float4 a = *(const float4*)(xr + e);
        float4 bb = *(const float4*)(bias + e);
        a.x += bb.x; a.y += bb.y; a.z += bb.z; a.w += bb.w;
#pragma unroll
        for (int z = 0; z < 2; z++) {
            f16x4 pz = *(const f16x4*)(part + (size_t)z * ROWS * EMB + (size_t)row * EMB + e);
            a.x += (float)pz[0]; a.y += (float)pz[1];
            a.z += (float)pz[2]; a.w += (float)pz[3];
        }
        v[t] = a;
        s += a.x + a.y + a.z + a.w;
    }
#pragma unroll
    for (int k = 1; k < 64; k <<= 1) s += __shfl_xor(s, k);
    float mu = s * (1.0f / EMB);
    float s2 = 0.f;
#pragma unroll
    for (int t = 0; t < 3; t++) {
        float dx = v[t].x - mu, dy = v[t].y - mu, dz = v[t].z - mu, dw = v[t].w - mu;
        s2 += dx * dx + dy * dy + dz * dz + dw * dw;
    }
#pragma unroll
    for (int k = 1; k < 64; k <<= 1) s2 += __shfl_xor(s2, k);
    float inv = rsqrtf(s2 * (1.0f / EMB) + 1e-5f);
    // LN2 result per element group
    float4 o2[3];
    float sF = 0.f;
#pragma unroll
    for (int t = 0; t < 3; t++) {
        int e = t * 256 + lane * 4;
        float4 wv = *(const float4*)(w + e);
        float4 bv = *(const float4*)(bsh + e);
        float4 o;
        o.x = (v[t].x - mu) * inv * wv.x + bv.x;
        o.y = (v[t].y - mu) * inv * wv.y + bv.y;
        o.z = (v[t].z - mu) * inv * wv.z + bv.z;
        o.w = (v[t].w - mu) * inv * wv.w + bv.w;
        o2[t] = o;
        if (FINAL) sF += o.x + o.y + o.z + o.w;
        else {
            *(float4*)(out32 + (size_t)row * EMB + e) = o;
            f16x4 hh;
            hh[0] = (f16)o.x; hh[1] = (f16)o.y; hh[2] = (f16)o.z; hh[3] = (f16)o.w;
            *(f16x4*)(out16 + (size_t)row * EMB + e) = hh;
        }
    }
    if (FINAL) {
#pragma unroll
        for (int k = 1; k < 64; k <<= 1) sF += __shfl_xor(sF, k);
        float muF = sF * (1.0f / EMB);
        float s2F = 0.f;
#pragma unroll
        for (int t = 0; t < 3; t++) {
            float dx = o2[t].x - muF, dy = o2[t].y - muF, dz = o2[t].z - muF, dw = o2[t].w - muF;
            s2F += dx * dx + dy * dy + dz * dz + dw * dw;
        }
#pragma unroll
        for (int k = 1; k < 64; k <<= 1) s2F += __shfl_xor(s2F, k);
        float invF = rsqrtf(s2F * (1.0f / EMB) + 1e-5f);
#pragma unroll
        for (int t = 0; t < 3; t++) {
            int e = t * 256 + lane * 4;
            float4 wv = *(const float4*)(wf + e);
            float4 bv = *(const float4*)(bf + e);
            float4 o;
            o.x = (o2[t].x - muF) * invF * wv.x + bv.x;
            o.y = (o2[t].y - muF) * invF * wv.y + bv.y;
            o.z = (o2[t].z - muF) * invF * wv.z + bv.z;
            o.w = (o2[t].w - muF) * invF * wv.w + bv.w;
            *(float4*)(out32 + (size_t)row * EMB + e) = o;
        }
    }
}

extern "C" void kernel_launch(void* const* d_in, const int* in_sizes, int n_in,
                              void* d_out, int out_size, void* d_ws, size_t ws_size,
                              hipStream_t stream) {
    const float* x      = (const float*)d_in[0];
    const float* tpe    = (const float*)d_in[2];
    const float* Wqkv   = (const float*)d_in[3];
    const float* bqkv   = (const float*)d_in[4];
    const float* W1     = (const float*)d_in[5];
    const float* b1     = (const float*)d_in[6];
    const float* W2     = (const float*)d_in[7];
    const float* b2     = (const float*)d_in[8];
    const float* ln1_w  = (const float*)d_in[9];
    const float* ln1_b  = (const float*)d_in[10];
    const float* ln2_w  = (const float*)d_in[11];
    const float* ln2_b  = (const float*)d_in[12];
    const float* lnf_w  = (const float*)d_in[13];
    const float* lnf_b  = (const float*)d_in[14];
    const int*   tt     = (const int*)d_in[15];
    const int*   rtc    = (const int*)d_in[16];
    float* out = (float*)d_out;

    // workspace layout (bytes)
    char* wsp = (char*)d_ws;
    float* h32  = (float*)wsp;                       //  6,291,456
    f16*   h16  = (f16*)(wsp + 6291456);             //  3,145,728
    f16*   act  = (f16*)(wsp + 9437184);             //  8,388,608 (qk 2048x1536 / ff1 2048x2048)
    f16*   vtg  = (f16*)(wsp + 17825792);            //  3,145,728 (B,H,64,S)
    f16*   part = (f16*)(wsp + 20971520);            //  6,291,456 (2x ROWS*EMB f16)
    f16*   wbuf = (f16*)(wsp + 27262976);            // 39,321,600 (ALL layers f16 weights)
    f16*   po   = (f16*)(wsp + 66584576);            //  3,145,728 (BH,SEQ,64 f16)
    u64*   mtab = (u64*)(wsp + 69730304);            //    131,072  -> total 69,861,376

    const int EQ = 3 * EMB * EMB;      // per-layer Wqkv elems
    const int E1 = FFDIM * EMB;        // per-layer W1 elems
    const int E2 = EMB * FFDIM;        // per-layer W2 elems
    f16* wqAll = wbuf;
    f16* w1All = wbuf + (size_t)NLAYER * EQ;
    f16* w2All = w1All + (size_t)NLAYER * E1;

    // one fused prep launch: all-layer weight cast + embed + mask table
    prep_kernel<<<4096, 256, 0, stream>>>(Wqkv, NLAYER * EQ / 4, W1, NLAYER * E1 / 4,
                                          W2, NLAYER * E2 / 4, wqAll, w1All, w2All,
                                          x, tpe, h32, h16, mtab, tt, rtc);

    for (int l = 0; l < NLAYER; l++) {
        const f16* wq16 = wqAll + (size_t)l * EQ;
        const f16* w116 = w1All + (size_t)l * E1;
        const f16* w216 = w2All + (size_t)l * E2;
        const float* bq  = bqkv + (size_t)l * 3 * EMB;
        const float* bb1 = b1 + (size_t)l * FFDIM;
        const float* bb2 = b2 + (size_t)l * EMB;

        // qkv: Q,K -> act (stride 1536), V -> vtg transposed (8-wave blocks)
        gemm_f16<0, 2><<<dim3(3 * EMB / 128, ROWS / 128), 512, 0, stream>>>(
            h16, wq16, bq, act, vtg, ROWS, 3 * EMB, EMB);

        // attention (full chain per q-tile, normalized in-kernel)
        attn_part<<<dim3(SEQ / 64, BH), 256, 0, stream>>>(act, vtg, mtab, po);

        // h = LN(h + attn_out)
        add_ln_attn<<<ROWS / 4, 256, 0, stream>>>(h32, po,
                                                  ln1_w + l * EMB, ln1_b + l * EMB, h32, h16);

        // ff1 = gelu(h @ W1^T + b1) -> act (f16, 2048x2048)
        gemm_f16<1, 1><<<dim3(FFDIM / 128, ROWS / 128), 512, 0, stream>>>(
            h16, w116, bb1, act, nullptr, ROWS, FFDIM, EMB);

        // ff2 partials: raw acc (f16) -> part[z], split-K x2 (K chunk = 1024)
        gemm_f16<0, 3><<<dim3(EMB / 128, ROWS / 128, 2), 512, 0, stream>>>(
            act, w216, nullptr, part, nullptr, ROWS, EMB, FFDIM);

        // h = LN(h + b2 + sum(part)); last layer also applies final LN -> out
        if (l < NLAYER - 1)
            add_ln_split<0><<<ROWS / 4, 256, 0, stream>>>(h32, part, bb2,
                ln2_w + l * EMB, ln2_b + l * EMB, nullptr, nullptr, h32, h16);
        else
            add_ln_split<1><<<ROWS / 4, 256, 0, stream>>>(h32, part, bb2,
                ln2_w + l * EMB, ln2_b + l * EMB, lnf_w, lnf_b, out, nullptr);
    }
}

// Round 17
// 385.291 us; speedup vs baseline: 1.1121x; 1.1121x over previous
//
#include <hip/hip_runtime.h>
#include <math.h>

#define SEQ 1024
#define EMB 768
#define NHEAD 12
#define HDIM 64
#define NLAYER 4
#define FFDIM 2048
#define BATCH 2
#define ROWS (BATCH * SEQ)   // 2048
#define BH (BATCH * NHEAD)   // 24
#define NCHUNK 2             // KV chunks of 8 tiles (512 keys)
#define CTILES 8             // j-tiles per chunk

using f16 = _Float16;
using f16x4 = __attribute__((ext_vector_type(4))) _Float16;
using f16x8 = __attribute__((ext_vector_type(8))) _Float16;
using f32x4 = __attribute__((ext_vector_type(4))) float;
using f32x16 = __attribute__((ext_vector_type(16))) float;
typedef unsigned long long u64;

__device__ inline void gload16(const void* g, void* l) {
    __builtin_amdgcn_global_load_lds((const __attribute__((address_space(1))) unsigned*)g,
                                     (__attribute__((address_space(3))) unsigned*)l, 16, 0, 0);
}

// ---------------- prep: weight cast (all layers) + embed + mask table -------
__global__ void prep_kernel(const float* __restrict__ Wq, int na,   // float4 units
                            const float* __restrict__ W1, int nb,
                            const float* __restrict__ W2, int nc,
                            f16* __restrict__ oq, f16* __restrict__ o1, f16* __restrict__ o2,
                            const float* __restrict__ x,
                            const float* __restrict__ tpe,
                            float* __restrict__ h32,
                            f16* __restrict__ h16,
                            u64* __restrict__ mtab,
                            const int* __restrict__ tt_p,
                            const int* __restrict__ rtc_p) {
    const int ncast = na + nb + nc;
    const int nembed = BATCH * SEQ * EMB;
    const int nmask = SEQ * 16;
    const int total = ncast + nembed + nmask;
    const int nt = *tt_p + 1;
    const int rtc = *rtc_p;
    for (int i = blockIdx.x * blockDim.x + threadIdx.x; i < total;
         i += gridDim.x * blockDim.x) {
        if (i < ncast) {
            const float* src;
            f16* dst;
            int off;
            if (i < na)            { src = Wq; dst = oq; off = i; }
            else if (i < na + nb)  { src = W1; dst = o1; off = i - na; }
            else                   { src = W2; dst = o2; off = i - na - nb; }
            float4 v = ((const float4*)src)[off];
            f16x4 o;
            o[0] = (f16)v.x; o[1] = (f16)v.y; o[2] = (f16)v.z; o[3] = (f16)v.w;
            ((f16x4*)dst)[off] = o;
        } else if (i < ncast + nembed) {
            int idx = i - ncast;
            int e = idx % EMB;
            int s = (idx / EMB) % SEQ;
            float val;
            if (s < rtc * nt) {
                int p = s / nt;
                int t = s % nt;
                int i2 = e & ~1;
                float div = __expf((float)i2 * -0.0119926314f);  // -ln(10000)/768
                float ang = (float)p * div;
                float pe = (e & 1) ? __cosf(ang) : __sinf(ang);
                val = x[idx] + pe + tpe[t * EMB + e];
            } else {
                val = 0.0f;
            }
            h32[idx] = val;
            h16[idx] = (f16)val;
        } else {
            int idx = i - ncast - nembed;
            int ii = idx >> 4, jt = idx & 15;
            int id = ii / nt, im = ii % nt;
            int iok = (ii < rtc * nt);
            u64 m = 0;
            for (int k = 0; k < 64; k++) {
                int j = jt * 64 + k;
                int jd = j / nt, jm = j % nt;
                bool same = (id == jd) && (id < rtc) && (im >= jm);
                bool sv   = (jm == 0) && (jd < rtc) && (ii > j) && iok;
                if (same || sv) m |= (1ull << k);
            }
            mtab[idx] = m;
        }
    }
}

// ---------------- MFMA GEMM (32x32x16): C = A @ W^T (+ bias) -----------------
// 512 threads = 8 waves sharing ONE staged 128x128 tile, output split 4(M)x2(N)
// per wave (32x64 each). LDS double-buffered (64KB -> 2 blocks/CU co-resident),
// prefetch-before-compute, ONE barrier per K-step.
// OUT: 1 = f16 out (+bias, opt GELU); 2 = qkv split (Q,K f16 stride 2E +bias,
//      V transposed +bias -> vtg[b,h,d,s]); 3 = f16 raw-acc partials to
//      Ch + z*ROWS*N (split-K; bias added downstream)
template<int ACT, int OUT>
__global__ __launch_bounds__(512) void gemm_f16(const f16* __restrict__ A,
                                                const f16* __restrict__ W,
                                                const float* __restrict__ bias,
                                                f16* __restrict__ Ch,
                                                f16* __restrict__ vtg,
                                                int M, int N, int K) {
    __shared__ f16 As[2][128 * 64];
    __shared__ f16 Ws[2][128 * 64];
    const int tid = threadIdx.x, lane = tid & 63, wave = tid >> 6;  // 0..7
    // XCD-aware block swizzle (bijective when nwg % 8 == 0)
    const int gx = gridDim.x;
    const int nwg = gx * gridDim.y;
    int orig = blockIdx.y * gx + blockIdx.x;
    int nid = (nwg & 7) ? orig : ((orig & 7) * (nwg >> 3) + (orig >> 3));
    const int bm = (nid / gx) * 128, bn = (nid % gx) * 128;
    const int l31 = lane & 31, l32 = lane >> 5;
    const int wm = (wave >> 1) * 32, wn = (wave & 1) * 64;  // wave's 32x64 sub-tile
    const int srow = lane >> 3, sslot = lane & 7;
    const int klen = K / gridDim.z;
    const int kbeg = blockIdx.z * klen;
    const int nsteps = klen >> 6;

    f32x16 acc[2];
#pragma unroll
    for (int ni = 0; ni < 2; ni++)
#pragma unroll
        for (int e = 0; e < 16; e++) acc[ni][e] = 0.f;

    // prologue: stage buffer 0 (8 waves x 16 rows each, A and W)
#pragma unroll
    for (int i = 0; i < 2; i++) {
        int R0 = wave * 16 + i * 8;
        int row = R0 + srow;
        int gs = (sslot ^ (row & 7)) << 3;
        gload16(A + (size_t)(bm + row) * K + kbeg + gs, As[0] + R0 * 64);
        gload16(W + (size_t)(bn + row) * K + kbeg + gs, Ws[0] + R0 * 64);
    }
    __syncthreads();

    int cur = 0;
    for (int t = 0; t < nsteps; t++) {
        if (t + 1 < nsteps) {
            int k1 = kbeg + (t + 1) * 64;
            int nxt = cur ^ 1;
#pragma unroll
            for (int i = 0; i < 2; i++) {
                int R0 = wave * 16 + i * 8;
                int row = R0 + srow;
                int gs = (sslot ^ (row & 7)) << 3;
                gload16(A + (size_t)(bm + row) * K + k1 + gs, As[nxt] + R0 * 64);
                gload16(W + (size_t)(bn + row) * K + k1 + gs, Ws[nxt] + R0 * 64);
            }
        }
#pragma unroll
        for (int ks = 0; ks < 4; ks++) {
            int kslot = ks * 2 + l32;   // 8 f16 k-elems per slot
            f16x8 a, b[2];
            {
                int row = wm + l31;
                a = *(const f16x8*)(As[cur] + row * 64 + ((kslot ^ (row & 7)) << 3));
            }
#pragma unroll
            for (int ni = 0; ni < 2; ni++) {
                int row = wn + ni * 32 + l31;
                b[ni] = *(const f16x8*)(Ws[cur] + row * 64 + ((kslot ^ (row & 7)) << 3));
            }
#pragma unroll
            for (int ni = 0; ni < 2; ni++)
                acc[ni] = __builtin_amdgcn_mfma_f32_32x32x16_f16(a, b[ni], acc[ni], 0, 0, 0);
        }
        __syncthreads();
        cur ^= 1;
    }

    // epilogue: C row = (reg&3) + 8*(reg>>2) + 4*(lane>>5), col = lane&31
#pragma unroll
    for (int ni = 0; ni < 2; ni++) {
        int nbase = bn + wn + ni * 32;
        int n = nbase + l31;
        if (OUT == 3) {
            f16* dst = Ch + (size_t)blockIdx.z * ROWS * N;
#pragma unroll
            for (int reg = 0; reg < 16; reg++) {
                int m = bm + wm + (reg & 3) + 8 * (reg >> 2) + 4 * l32;
                dst[(size_t)m * N + n] = (f16)acc[ni][reg];
            }
        } else {
            float bv = bias[n];
            if (OUT != 2 || nbase < 2 * EMB) {
                int cstride = (OUT == 2) ? 2 * EMB : N;
#pragma unroll
                for (int reg = 0; reg < 16; reg++) {
                    int m = bm + wm + (reg & 3) + 8 * (reg >> 2) + 4 * l32;
                    float v = acc[ni][reg] + bv;
                    if (ACT) v = 0.5f * v * (1.0f + erff(v * 0.70710678118654752f));
                    Ch[(size_t)m * cstride + n] = (f16)v;
                }
            } else {
                // V third: write transposed vtg[((b*H + h)*64 + d) * SEQ + s]
                int d = n - 2 * EMB;
                int hh = d >> 6, dd = d & 63;
#pragma unroll
                for (int q = 0; q < 4; q++) {
                    int m0 = bm + wm + 8 * q + 4 * l32;
                    int bb = m0 >> 10, s0 = m0 & (SEQ - 1);
                    f16x4 pack;
#pragma unroll
                    for (int r = 0; r < 4; r++) pack[r] = (f16)(acc[ni][4 * q + r] + bv);
                    *(f16x4*)(vtg + ((size_t)((bb * NHEAD + hh) * HDIM + dd)) * SEQ + s0) = pack;
                }
            }
        }
    }
}

// ---------------- flash attention partials (split-KV, dbuf, mask table) -----
// grid: (NCHUNK, S/64, BH); qt reversed (long chains first).
// K/V staged to LDS (shared by all 4 waves, coalesced gload16), double-
// buffered with prefetch-before-compute. lsum via matrix-pipe row-sum.
__global__ __launch_bounds__(256) void attn_part(const f16* __restrict__ qk,  // (B*S, 2E)
                                                 const f16* __restrict__ vtg, // (B,H,64,S)
                                                 const u64* __restrict__ mtab,// [SEQ][16]
                                                 f16* __restrict__ po,        // [NCHUNK][BH][SEQ][64]
                                                 float* __restrict__ pm,      // [NCHUNK][BH][SEQ]
                                                 float* __restrict__ pl) {
    const int c = blockIdx.x;
    const int qt = gridDim.y - 1 - blockIdx.y;   // long chains first
    if (c * CTILES > qt) return;
    const int bh = blockIdx.z;
    const int b = bh / NHEAD, hh = bh % NHEAD;
    const int q0 = qt * 64;
    const int jt_beg = c * CTILES, jt_end = min(qt, c * CTILES + CTILES - 1);

    __shared__ f16 Qs[64 * 64];
    __shared__ f16 Ks[2][64 * 64];
    __shared__ f16 VT[2][64 * 64];
    __shared__ f16 Ps[4 * 16 * 64];

    const int tid = threadIdx.x, lane = tid & 63, wave = tid >> 6;
    const int l15 = lane & 15, l16 = lane >> 4;
    const int RS = 2 * EMB;
    const f16* vth = vtg + (size_t)(b * NHEAD + hh) * HDIM * SEQ;
    const float SCALE2 = 0.125f * 1.44269504088896f;   // scale * log2(e)

    // ---- stage Q tile + first K/V tile (pre-swizzled source) ----
#pragma unroll
    for (int it = 0; it < 2; it++) {
        int R0 = wave * 16 + it * 8;
        int row = R0 + (lane >> 3), slot = lane & 7;
        int gs = (slot ^ (row & 7)) << 3;
        gload16(qk + (size_t)(b * SEQ + q0 + row) * RS + hh * HDIM + gs, Qs + R0 * 64);
        gload16(qk + (size_t)(b * SEQ + jt_beg * 64 + row) * RS + EMB + hh * HDIM + gs,
                Ks[0] + R0 * 64);
        gload16(vth + (size_t)row * SEQ + jt_beg * 64 + gs, VT[0] + R0 * 64);
    }
    __syncthreads();

    f16x8 qa[2];
#pragma unroll
    for (int ks = 0; ks < 2; ks++) {
        int row = wave * 16 + l15;
        int kslot = l16 + ks * 4;
        qa[ks] = *(const f16x8*)(Qs + row * 64 + ((kslot ^ (row & 7)) << 3));
    }

    f16x8 ones;
#pragma unroll
    for (int i = 0; i < 8; i++) ones[i] = (f16)1.0f;

    float mrow[4];
    f32x4 o[4], osum;
    int iglob[4];
#pragma unroll
    for (int r = 0; r < 4; r++) {
        mrow[r] = -1e30f;
        iglob[r] = q0 + wave * 16 + l16 * 4 + r;
    }
#pragma unroll
    for (int nf = 0; nf < 4; nf++) o[nf] = (f32x4){0.f, 0.f, 0.f, 0.f};
    osum = (f32x4){0.f, 0.f, 0.f, 0.f};

    for (int jt = jt_beg; jt <= jt_end; jt++) {
        const int cur = (jt - jt_beg) & 1;
        // ---- issue next tile's async loads (hidden under compute) ----
        if (jt < jt_end) {
            const int nxt = cur ^ 1;
            const int jn0 = (jt + 1) * 64;
#pragma unroll
            for (int it = 0; it < 2; it++) {
                int R0 = wave * 16 + it * 8;
                int row = R0 + (lane >> 3), slot = lane & 7;
                int gs = (slot ^ (row & 7)) << 3;
                gload16(qk + (size_t)(b * SEQ + jn0 + row) * RS + EMB + hh * HDIM + gs,
                        Ks[nxt] + R0 * 64);
                gload16(vth + (size_t)row * SEQ + jn0 + gs, VT[nxt] + R0 * 64);
            }
        }

        // ---- fetch mask words for this j-tile ----
        unsigned mlo[4], mhi[4];
#pragma unroll
        for (int r = 0; r < 4; r++) {
            u64 mk = mtab[iglob[r] * 16 + jt];
            mlo[r] = (unsigned)mk;
            mhi[r] = (unsigned)(mk >> 32);
        }

        // ---- S = Q K^T ----
        f32x4 s[4];
        __builtin_amdgcn_s_setprio(1);
#pragma unroll
        for (int nf = 0; nf < 4; nf++) {
            s[nf] = (f32x4){0.f, 0.f, 0.f, 0.f};
#pragma unroll
            for (int ks = 0; ks < 2; ks++) {
                int row = nf * 16 + l15;
                int kslot = l16 + ks * 4;
                f16x8 kb = *(const f16x8*)(Ks[cur] + row * 64 + ((kslot ^ (row & 7)) << 3));
                s[nf] = __builtin_amdgcn_mfma_f32_16x16x32_f16(qa[ks], kb, s[nf], 0, 0, 0);
            }
        }
        __builtin_amdgcn_s_setprio(0);

        // ---- mask (bit-table) + online softmax (base-2) ----
        float p[4][4];
        float tmax[4] = {-1e30f, -1e30f, -1e30f, -1e30f};
#pragma unroll
        for (int nf = 0; nf < 4; nf++) {
            int sh = (nf & 1) * 16 + l15;
#pragma unroll
            for (int r = 0; r < 4; r++) {
                unsigned w = (nf & 2) ? mhi[r] : mlo[r];
                bool allowed = (w >> sh) & 1;
                float val = allowed ? s[nf][r] * SCALE2 : -1e30f;
                p[nf][r] = val;
                tmax[r] = fmaxf(tmax[r], val);
            }
        }
#pragma unroll
        for (int r = 0; r < 4; r++) {
            tmax[r] = fmaxf(tmax[r], __shfl_xor(tmax[r], 1));
            tmax[r] = fmaxf(tmax[r], __shfl_xor(tmax[r], 2));
            tmax[r] = fmaxf(tmax[r], __shfl_xor(tmax[r], 4));
            tmax[r] = fmaxf(tmax[r], __shfl_xor(tmax[r], 8));
        }
        float alpha[4], meff[4];
#pragma unroll
        for (int r = 0; r < 4; r++) {
            float mn = fmaxf(mrow[r], tmax[r]);
            alpha[r] = exp2f(mrow[r] - mn);
            mrow[r] = mn;
            meff[r] = (mn <= -1e29f) ? 0.f : mn;
        }
#pragma unroll
        for (int nf = 0; nf < 4; nf++)
#pragma unroll
            for (int r = 0; r < 4; r++)
                p[nf][r] = exp2f(p[nf][r] - meff[r]);
#pragma unroll
        for (int r = 0; r < 4; r++) osum[r] *= alpha[r];
#pragma unroll
        for (int nf = 0; nf < 4; nf++)
#pragma unroll
            for (int r = 0; r < 4; r++) o[nf][r] *= alpha[r];

        // ---- P -> per-wave LDS (wave-local, lgkm-ordered) ----
        f16* P = Ps + wave * 16 * 64;
#pragma unroll
        for (int nf = 0; nf < 4; nf++)
#pragma unroll
            for (int r = 0; r < 4; r++) {
                int prow = l16 * 4 + r;
                int pcol = nf * 16 + l15;
                P[prow * 64 + (((pcol >> 3) ^ (prow & 7)) << 3) + (pcol & 7)] = (f16)p[nf][r];
            }

        // ---- O += P @ V ; lsum += P @ 1 (matrix pipe row-sum) ----
        __builtin_amdgcn_s_setprio(1);
#pragma unroll
        for (int ks = 0; ks < 2; ks++) {
            int kslot = l16 + ks * 4;
            int prow = l15;
            f16x8 pa = *(const f16x8*)(P + prow * 64 + ((kslot ^ (prow & 7)) << 3));
            osum = __builtin_amdgcn_mfma_f32_16x16x32_f16(pa, ones, osum, 0, 0, 0);
#pragma unroll
            for (int nf = 0; nf < 4; nf++) {
                int vrow = nf * 16 + l15;
                f16x8 vb = *(const f16x8*)(VT[cur] + vrow * 64 + ((kslot ^ (vrow & 7)) << 3));
                o[nf] = __builtin_amdgcn_mfma_f32_16x16x32_f16(pa, vb, o[nf], 0, 0, 0);
            }
        }
        __builtin_amdgcn_s_setprio(0);
        __syncthreads();
    }

    // ---- write partials (unnormalized) ----
    const size_t base = (size_t)(c * BH + bh) * SEQ;
#pragma unroll
    for (int r = 0; r < 4; r++) {
        int i = q0 + wave * 16 + l16 * 4 + r;
#pragma unroll
        for (int nf = 0; nf < 4; nf++)
            po[(base + i) * 64 + nf * 16 + l15] = (f16)o[nf][r];
        if (l15 == 0) {
            pm[base + i] = mrow[r];
            pl[base + i] = osum[r];
        }
    }
}

// ---------------- LN( h + attn_combine(po,pm,pl) ), wave-per-row ------------
__global__ __launch_bounds__(256) void add_ln_attn(const float* __restrict__ X,
                                                   const f16* __restrict__ po,
                                                   const float* __restrict__ pm,
                                                   const float* __restrict__ pl,
                                                   const float* __restrict__ w,
                                                   const float* __restrict__ bsh,
                                                   float* __restrict__ out32,
                                                   f16* __restrict__ out16) {
    const int row = blockIdx.x * 4 + (threadIdx.x >> 6);
    const int lane = threadIdx.x & 63;
    const int b = row >> 10, i = row & (SEQ - 1);
    const int nch = (i >> 6) / CTILES + 1;   // chunks with CTILES*c <= qt
    const float* xr = X + (size_t)row * EMB;
    float4 v[3];
    float s = 0.f;
#pragma unroll
    for (int t = 0; t < 3; t++) {
        int e = t * 256 + lane * 4;
        int hh = e >> 6, d = e & 63;
        size_t hbase = (size_t)(b * NHEAD + hh) * SEQ + i;
        float m = -1e30f;
        for (int c = 0; c < nch; c++) m = fmaxf(m, pm[hbase + (size_t)c * BH * SEQ]);
        float meff = (m <= -1e29f) ? 0.f : m;
        float lt = 0.f;
        float4 ov = {0.f, 0.f, 0.f, 0.f};
        for (int c = 0; c < nch; c++) {
            size_t idx = hbase + (size_t)c * BH * SEQ;
            float wgt = exp2f(pm[idx] - meff);
            lt += pl[idx] * wgt;
            f16x4 pv = *(const f16x4*)(po + idx * 64 + d);
            ov.x += (float)pv[0] * wgt; ov.y += (float)pv[1] * wgt;
            ov.z += (float)pv[2] * wgt; ov.w += (float)pv[3] * wgt;
        }
        float inv = (lt > 0.f) ? 1.0f / lt : 0.0f;
        float4 a = *(const float4*)(xr + e);
        a.x += ov.x * inv; a.y += ov.y * inv; a.z += ov.z * inv; a.w += ov.w * inv;
        v[t] = a;
        s += a.x + a.y + a.z + a.w;
    }
#pragma unroll
    for (int k = 1; k < 64; k <<= 1) s += __shfl_xor(s, k);
    float mu = s * (1.0f / EMB);
    float s2 = 0.f;
#pragma unroll
    for (int t = 0; t < 3; t++) {
        float dx = v[t].x - mu, dy = v[t].y - mu, dz = v[t].z - mu, dw = v[t].w - mu;
        s2 += dx * dx + dy * dy + dz * dz + dw * dw;
    }
#pragma unroll
    for (int k = 1; k < 64; k <<= 1) s2 += __shfl_xor(s2, k);
    float inv = rsqrtf(s2 * (1.0f / EMB) + 1e-5f);
#pragma unroll
    for (int t = 0; t < 3; t++) {
        int e = t * 256 + lane * 4;
        float4 wv = *(const float4*)(w + e);
        float4 bv = *(const float4*)(bsh + e);
        float4 o;
        o.x = (v[t].x - mu) * inv * wv.x + bv.x;
        o.y = (v[t].y - mu) * inv * wv.y + bv.y;
        o.z = (v[t].z - mu) * inv * wv.z + bv.z;
        o.w = (v[t].w - mu) * inv * wv.w + bv.w;
        *(float4*)(out32 + (size_t)row * EMB + e) = o;
        f16x4 hh;
        hh[0] = (f16)o.x; hh[1] = (f16)o.y; hh[2] = (f16)o.z; hh[3] = (f16)o.w;
        *(f16x4*)(out16 + (size_t)row * EMB + e) = hh;
    }
}

// ---------------- LN( h + bias + sum of 4 f16 split-K partials ) ------------
// FINAL=1: additionally apply the final LayerNorm (lnf) in-register and write
// ONLY the f32 output (fuses the last ln_final launch).
template<int FINAL>
__global__ __launch_bounds__(256) void add_ln_split4(const float* __restrict__ X,
                                                     const f16* __restrict__ part, // 4x ROWS*EMB f16
                                                     const float* __restrict__ bias,
                                                     const float* __restrict__ w,
                                                     const float* __restrict__ bsh,
                                                     const float* __restrict__ wf,   // lnf
                                                     const float* __restrict__ bf,
                                                     float* __restrict__ out32,
                                                     f16* __restrict__ out16) {
    const int row = blockIdx.x * 4 + (threadIdx.x >> 6);
    const int lane = threadIdx.x & 63;
    const float* xr = X + (size_t)row * EMB;
    float4 v[3];
    float s = 0.f;
#pragma unroll
    for (int t = 0; t < 3; t++) {
        int e = t * 256 + lane * 4;
        float4 a = *(const float4*)(xr + e);
        float4 bb = *(const float4*)(bias + e);
        a.x += bb.x; a.y += bb.y; a.z += bb.z; a.w += bb.w;
#pragma unroll
        for (int z = 0; z < 4; z++) {
            f16x4 pz = *(const f16x4*)(part + (size_t)z * ROWS * EMB + (size_t)row * EMB + e);
            a.x += (float)pz[0]; a.y += (float)pz[1];
            a.z += (float)pz[2]; a.w += (float)pz[3];
        }
        v[t] = a;
        s += a.x + a.y + a.z + a.w;
    }
#pragma unroll
    for (int k = 1; k < 64; k <<= 1) s += __shfl_xor(s, k);
    float mu = s * (1.0f / EMB);
    float s2 = 0.f;
#pragma unroll
    for (int t = 0; t < 3; t++) {
        float dx = v[t].x - mu, dy = v[t].y - mu, dz = v[t].z - mu, dw = v[t].w - mu;
        s2 += dx * dx + dy * dy + dz * dz + dw * dw;
    }
#pragma unroll
    for (int k = 1; k < 64; k <<= 1) s2 += __shfl_xor(s2, k);
    float inv = rsqrtf(s2 * (1.0f / EMB) + 1e-5f);
    // LN2 result per element group
    float4 o2[3];
    float sF = 0.f;
#pragma unroll
    for (int t = 0; t < 3; t++) {
        int e = t * 256 + lane * 4;
        float4 wv = *(const float4*)(w + e);
        float4 bv = *(const float4*)(bsh + e);
        float4 o;
        o.x = (v[t].x - mu) * inv * wv.x + bv.x;
        o.y = (v[t].y - mu) * inv * wv.y + bv.y;
        o.z = (v[t].z - mu) * inv * wv.z + bv.z;
        o.w = (v[t].w - mu) * inv * wv.w + bv.w;
        o2[t] = o;
        if (FINAL) sF += o.x + o.y + o.z + o.w;
        else {
            *(float4*)(out32 + (size_t)row * EMB + e) = o;
            f16x4 hh;
            hh[0] = (f16)o.x; hh[1] = (f16)o.y; hh[2] = (f16)o.z; hh[3] = (f16)o.w;
            *(f16x4*)(out16 + (size_t)row * EMB + e) = hh;
        }
    }
    if (FINAL) {
#pragma unroll
        for (int k = 1; k < 64; k <<= 1) sF += __shfl_xor(sF, k);
        float muF = sF * (1.0f / EMB);
        float s2F = 0.f;
#pragma unroll
        for (int t = 0; t < 3; t++) {
            float dx = o2[t].x - muF, dy = o2[t].y - muF, dz = o2[t].z - muF, dw = o2[t].w - muF;
            s2F += dx * dx + dy * dy + dz * dz + dw * dw;
        }
#pragma unroll
        for (int k = 1; k < 64; k <<= 1) s2F += __shfl_xor(s2F, k);
        float invF = rsqrtf(s2F * (1.0f / EMB) + 1e-5f);
#pragma unroll
        for (int t = 0; t < 3; t++) {
            int e = t * 256 + lane * 4;
            float4 wv = *(const float4*)(wf + e);
            float4 bv = *(const float4*)(bf + e);
            float4 o;
            o.x = (o2[t].x - muF) * invF * wv.x + bv.x;
            o.y = (o2[t].y - muF) * invF * wv.y + bv.y;
            o.z = (o2[t].z - muF) * invF * wv.z + bv.z;
            o.w = (o2[t].w - muF) * invF * wv.w + bv.w;
            *(float4*)(out32 + (size_t)row * EMB + e) = o;
        }
    }
}

extern "C" void kernel_launch(void* const* d_in, const int* in_sizes, int n_in,
                              void* d_out, int out_size, void* d_ws, size_t ws_size,
                              hipStream_t stream) {
    const float* x      = (const float*)d_in[0];
    const float* tpe    = (const float*)d_in[2];
    const float* Wqkv   = (const float*)d_in[3];
    const float* bqkv   = (const float*)d_in[4];
    const float* W1     = (const float*)d_in[5];
    const float* b1     = (const float*)d_in[6];
    const float* W2     = (const float*)d_in[7];
    const float* b2     = (const float*)d_in[8];
    const float* ln1_w  = (const float*)d_in[9];
    const float* ln1_b  = (const float*)d_in[10];
    const float* ln2_w  = (const float*)d_in[11];
    const float* ln2_b  = (const float*)d_in[12];
    const float* lnf_w  = (const float*)d_in[13];
    const float* lnf_b  = (const float*)d_in[14];
    const int*   tt     = (const int*)d_in[15];
    const int*   rtc    = (const int*)d_in[16];
    float* out = (float*)d_out;

    // workspace layout (bytes)
    char* wsp = (char*)d_ws;
    float* h32  = (float*)wsp;                       //  6,291,456
    f16*   h16  = (f16*)(wsp + 6291456);             //  3,145,728
    f16*   act  = (f16*)(wsp + 9437184);             //  8,388,608 (qk 2048x1536 / ff1 2048x2048)
    f16*   vtg  = (f16*)(wsp + 17825792);            //  3,145,728 (B,H,64,S)
    f16*   part = (f16*)(wsp + 20971520);            // 12,582,912 (4x ROWS*EMB f16)
    f16*   wbuf = (f16*)(wsp + 33554432);            // 39,321,600 (ALL layers f16 weights)
    f16*   po   = (f16*)(wsp + 72876032);            //  6,291,456 (NCHUNK=2)
    float* pm   = (float*)(wsp + 79167488);          //    196,608
    float* pl   = (float*)(wsp + 79364096);          //    196,608
    u64*   mtab = (u64*)(wsp + 79560704);            //    131,072  -> total 79,691,776

    const int EQ = 3 * EMB * EMB;      // per-layer Wqkv elems
    const int E1 = FFDIM * EMB;        // per-layer W1 elems
    const int E2 = EMB * FFDIM;        // per-layer W2 elems
    f16* wqAll = wbuf;
    f16* w1All = wbuf + (size_t)NLAYER * EQ;
    f16* w2All = w1All + (size_t)NLAYER * E1;

    // one fused prep launch: all-layer weight cast + embed + mask table
    prep_kernel<<<4096, 256, 0, stream>>>(Wqkv, NLAYER * EQ / 4, W1, NLAYER * E1 / 4,
                                          W2, NLAYER * E2 / 4, wqAll, w1All, w2All,
                                          x, tpe, h32, h16, mtab, tt, rtc);

    for (int l = 0; l < NLAYER; l++) {
        const f16* wq16 = wqAll + (size_t)l * EQ;
        const f16* w116 = w1All + (size_t)l * E1;
        const f16* w216 = w2All + (size_t)l * E2;
        const float* bq  = bqkv + (size_t)l * 3 * EMB;
        const float* bb1 = b1 + (size_t)l * FFDIM;
        const float* bb2 = b2 + (size_t)l * EMB;

        // qkv: Q,K -> act (stride 1536), V -> vtg transposed (8-wave blocks)
        gemm_f16<0, 2><<<dim3(3 * EMB / 128, ROWS / 128), 512, 0, stream>>>(
            h16, wq16, bq, act, vtg, ROWS, 3 * EMB, EMB);

        // attention partials (2 chunks of 8 tiles, LDS-staged dbuf)
        attn_part<<<dim3(NCHUNK, SEQ / 64, BH), 256, 0, stream>>>(act, vtg, mtab, po, pm, pl);

        // h = LN(h + combine(po)) — combine fused into LN
        add_ln_attn<<<ROWS / 4, 256, 0, stream>>>(h32, po, pm, pl,
                                                  ln1_w + l * EMB, ln1_b + l * EMB, h32, h16);

        // ff1 = gelu(h @ W1^T + b1) -> act (f16, 2048x2048)
        gemm_f16<1, 1><<<dim3(FFDIM / 128, ROWS / 128), 512, 0, stream>>>(
            h16, w116, bb1, act, nullptr, ROWS, FFDIM, EMB);

        // ff2 partials: raw acc (f16) -> part[z], split-K x4 (K chunk = 512)
        gemm_f16<0, 3><<<dim3(EMB / 128, ROWS / 128, 4), 512, 0, stream>>>(
            act, w216, nullptr, part, nullptr, ROWS, EMB, FFDIM);

        // h = LN(h + b2 + sum(part)); last layer also applies final LN -> out
        if (l < NLAYER - 1)
            add_ln_split4<0><<<ROWS / 4, 256, 0, stream>>>(h32, part, bb2,
                ln2_w + l * EMB, ln2_b + l * EMB, nullptr, nullptr, h32, h16);
        else
            add_ln_split4<1><<<ROWS / 4, 256, 0, stream>>>(h32, part, bb2,
                ln2_w + l * EMB, ln2_b + l * EMB, lnf_w, lnf_b, out, nullptr);
    }
}